// Round 3
// baseline (418.708 us; speedup 1.0000x reference)
//
#include <hip/hip_runtime.h>
#include <hip/hip_bf16.h>
#include <stdint.h>

// MHA: B=1, L=4096, D=1024, H=16, dk=64.
// Inputs fp32, OUTPUT fp32 (reference returns float32; comparison at bf16
// tolerance). Internal compute bf16 with fp32 accumulation.

typedef __bf16 bf16_t;
typedef __bf16 bf16x8 __attribute__((ext_vector_type(8)));
typedef float f32x4 __attribute__((ext_vector_type(4)));

#define MFMA_BF16 __builtin_amdgcn_mfma_f32_16x16x32_bf16

__device__ __forceinline__ void async_copy16(const void* g, void* lds) {
  // global -> LDS direct copy, 16B/lane; LDS dest = wave-uniform base + lane*16
  __builtin_amdgcn_global_load_lds(
      (__attribute__((address_space(1))) void*)(uintptr_t)g,
      (__attribute__((address_space(3))) void*)lds, 16, 0, 0);
}

// ---------------------------------------------------------------------------
// fp32 -> bf16 cast, 8 elems/thread, z selects tensor.
// ---------------------------------------------------------------------------
__global__ __launch_bounds__(256) void cast_f32_bf16(
    const float* __restrict__ s0, bf16_t* __restrict__ d0, int n0,
    const float* __restrict__ s1, bf16_t* __restrict__ d1, int n1,
    const float* __restrict__ s2, bf16_t* __restrict__ d2, int n2,
    const float* __restrict__ s3, bf16_t* __restrict__ d3, int n3,
    const float* __restrict__ s4, bf16_t* __restrict__ d4, int n4,
    const float* __restrict__ s5, bf16_t* __restrict__ d5, int n5,
    const float* __restrict__ s6, bf16_t* __restrict__ d6, int n6) {
  const float* s;
  bf16_t* d;
  int n;
  switch (blockIdx.z) {
    case 0: s = s0; d = d0; n = n0; break;
    case 1: s = s1; d = d1; n = n1; break;
    case 2: s = s2; d = d2; n = n2; break;
    case 3: s = s3; d = d3; n = n3; break;
    case 4: s = s4; d = d4; n = n4; break;
    case 5: s = s5; d = d5; n = n5; break;
    default: s = s6; d = d6; n = n6; break;
  }
  const int i = (blockIdx.x * 256 + threadIdx.x) * 8;
  if (i >= n) return;
  float4 a = *(const float4*)(s + i);
  float4 b = *(const float4*)(s + i + 4);
  bf16x8 o;
  o[0] = (bf16_t)a.x; o[1] = (bf16_t)a.y; o[2] = (bf16_t)a.z; o[3] = (bf16_t)a.w;
  o[4] = (bf16_t)b.x; o[5] = (bf16_t)b.y; o[6] = (bf16_t)b.z; o[7] = (bf16_t)b.w;
  *(bf16x8*)(d + i) = o;
}

// ---------------------------------------------------------------------------
// GEMM: C[m][n] = sum_k A[m][k] * W[n][k] + bias[n]   (C = A @ W^T + b)
// Tile 128x64, BK=32, 256 threads = 4 waves in 2x2 grid.
// blockIdx.z selects one of up to 3 independent problem sets.
// CT = output element type (bf16 for intermediates, float for final output).
// ---------------------------------------------------------------------------
template <typename CT>
__global__ __launch_bounds__(256) void gemm3_bt(
    const bf16_t* __restrict__ A0, const bf16_t* __restrict__ W0,
    const float* __restrict__ b0, CT* __restrict__ C0,
    const bf16_t* __restrict__ A1, const bf16_t* __restrict__ W1,
    const float* __restrict__ b1, CT* __restrict__ C1,
    const bf16_t* __restrict__ A2, const bf16_t* __restrict__ W2,
    const float* __restrict__ b2, CT* __restrict__ C2,
    int M, int N, int K) {
  const bf16_t *A, *W;
  const float* bias;
  CT* C;
  if (blockIdx.z == 0)      { A = A0; W = W0; bias = b0; C = C0; }
  else if (blockIdx.z == 1) { A = A1; W = W1; bias = b1; C = C1; }
  else                      { A = A2; W = W2; bias = b2; C = C2; }

  __shared__ bf16_t As[128][32];  // 8 KB, row = 64B -> 2-way bank alias (free)
  __shared__ bf16_t Bs[64][32];   // 4 KB

  const int t = threadIdx.x;
  const int w = t >> 6, lane = t & 63;
  const int quad = lane >> 4, l16 = lane & 15;
  const int wr = w >> 1, wc = w & 1;  // 2x2 wave grid
  const int m0 = blockIdx.x * 128;
  const int n0 = blockIdx.y * 64;

  // staging: one "unit" = 16 rows x 32 cols = 1KB = 64 lanes x 16B
  const int srow = lane >> 2;        // 0..15 within unit
  const int scol = (lane & 3) * 8;   // 0,8,16,24

  f32x4 acc[4][2] = {};  // [mt][nt]

  for (int k0 = 0; k0 < K; k0 += 32) {
    async_copy16(&A[(size_t)(m0 + (2 * w) * 16 + srow) * K + k0 + scol],
                 (char*)As + (2 * w) * 1024);
    async_copy16(&A[(size_t)(m0 + (2 * w + 1) * 16 + srow) * K + k0 + scol],
                 (char*)As + (2 * w + 1) * 1024);
    async_copy16(&W[(size_t)(n0 + w * 16 + srow) * K + k0 + scol],
                 (char*)Bs + w * 1024);
    __syncthreads();  // drains vmcnt (global_load_lds) + lgkmcnt

    bf16x8 af[4], bfr[2];
#pragma unroll
    for (int mt = 0; mt < 4; mt++)
      af[mt] = *(const bf16x8*)&As[wr * 64 + mt * 16 + l16][quad * 8];
#pragma unroll
    for (int nt = 0; nt < 2; nt++)
      bfr[nt] = *(const bf16x8*)&Bs[wc * 32 + nt * 16 + l16][quad * 8];
#pragma unroll
    for (int mt = 0; mt < 4; mt++)
#pragma unroll
      for (int nt = 0; nt < 2; nt++)
        acc[mt][nt] = MFMA_BF16(af[mt], bfr[nt], acc[mt][nt], 0, 0, 0);
    __syncthreads();  // protect LDS before next stage
  }

  // epilogue: C/D layout col = lane&15, row = quad*4 + r  (m89-verified)
#pragma unroll
  for (int nt = 0; nt < 2; nt++) {
    const int col = n0 + wc * 32 + nt * 16 + l16;
    const float bb = bias[col];
#pragma unroll
    for (int mt = 0; mt < 4; mt++) {
#pragma unroll
      for (int r = 0; r < 4; r++) {
        const int row = m0 + wr * 64 + mt * 16 + quad * 4 + r;
        C[(size_t)row * N + col] = (CT)(acc[mt][nt][r] + bb);
      }
    }
  }
}

// ---------------------------------------------------------------------------
// Transpose V [4096][1024] -> Vt [H*64][4096]  (pure bit move)
// ---------------------------------------------------------------------------
__global__ __launch_bounds__(256) void transpose_v(
    const ushort* __restrict__ V, ushort* __restrict__ Vt) {
  __shared__ ushort Ts[64][72];  // +8 pad breaks column-read conflicts
  const int h = blockIdx.y;
  const int l0 = blockIdx.x * 64;
  const int t = threadIdx.x;
  const int r = t >> 4;          // 0..15
  const int c4 = (t & 15) * 4;   // 0..60

#pragma unroll
  for (int i = 0; i < 4; i++) {
    const int row = i * 16 + r;
    ushort4 v = *(const ushort4*)&V[(size_t)(l0 + row) * 1024 + h * 64 + c4];
    Ts[row][c4 + 0] = v.x; Ts[row][c4 + 1] = v.y;
    Ts[row][c4 + 2] = v.z; Ts[row][c4 + 3] = v.w;
  }
  __syncthreads();
#pragma unroll
  for (int i = 0; i < 4; i++) {
    const int j = i * 16 + r;     // dk index within head
    const int l4 = (t & 15) * 4;  // sequence offset
    ushort4 o4;
    o4.x = Ts[l4 + 0][j]; o4.y = Ts[l4 + 1][j];
    o4.z = Ts[l4 + 2][j]; o4.w = Ts[l4 + 3][j];
    *(ushort4*)&Vt[(size_t)(h * 64 + j) * 4096 + l0 + l4] = o4;
  }
}

// ---------------------------------------------------------------------------
// Flash attention.  Block = 4 waves; wave owns 32 q-rows (2 m-tiles) of one
// head; KV chunk = 64.  Q pre-scaled by 1/8.  Online softmax; per-lane
// partial row-sum (alpha-rescaled), reduced once at the end.
// ---------------------------------------------------------------------------
__global__ __launch_bounds__(256) void flash_attn(
    const bf16_t* __restrict__ Q, const bf16_t* __restrict__ K,
    const bf16_t* __restrict__ Vt, bf16_t* __restrict__ O, int L) {
  const int h = blockIdx.y;
  const int q0 = blockIdx.x * 128;
  const int t = threadIdx.x;
  const int w = t >> 6, lane = t & 63;
  const int quad = lane >> 4, l16 = lane & 15;
  const int qbase = q0 + w * 32;

  __shared__ bf16_t Pbuf[4][2][16][72];  // [wave][mt][row][kv+pad] = 18 KB

  bf16x8 qa[2][2];
#pragma unroll
  for (int mt = 0; mt < 2; mt++)
#pragma unroll
    for (int kc = 0; kc < 2; kc++) {
      bf16x8 v = *(const bf16x8*)&Q[(size_t)(qbase + mt * 16 + l16) * 1024 +
                                    h * 64 + kc * 32 + quad * 8];
#pragma unroll
      for (int j = 0; j < 8; j++) v[j] = (bf16_t)((float)v[j] * 0.125f);
      qa[mt][kc] = v;
    }

  f32x4 o[2][4] = {};  // [mt][dt]
  float mst[2][4], lsum[2][4];
#pragma unroll
  for (int mt = 0; mt < 2; mt++)
#pragma unroll
    for (int r = 0; r < 4; r++) { mst[mt][r] = -1e30f; lsum[mt][r] = 0.f; }

  for (int j0 = 0; j0 < L; j0 += 64) {
    bf16x8 kb[4][2];
#pragma unroll
    for (int tt = 0; tt < 4; tt++)
#pragma unroll
      for (int kc = 0; kc < 2; kc++)
        kb[tt][kc] = *(const bf16x8*)&K[(size_t)(j0 + tt * 16 + l16) * 1024 +
                                        h * 64 + kc * 32 + quad * 8];
    f32x4 s[2][4];
#pragma unroll
    for (int mt = 0; mt < 2; mt++)
#pragma unroll
      for (int tt = 0; tt < 4; tt++) {
        f32x4 z = {0.f, 0.f, 0.f, 0.f};
        z = MFMA_BF16(qa[mt][0], kb[tt][0], z, 0, 0, 0);
        z = MFMA_BF16(qa[mt][1], kb[tt][1], z, 0, 0, 0);
        s[mt][tt] = z;
      }

#pragma unroll
    for (int mt = 0; mt < 2; mt++) {
#pragma unroll
      for (int r = 0; r < 4; r++) {
        float tm = fmaxf(fmaxf(s[mt][0][r], s[mt][1][r]),
                         fmaxf(s[mt][2][r], s[mt][3][r]));
        tm = fmaxf(tm, __shfl_xor(tm, 1));
        tm = fmaxf(tm, __shfl_xor(tm, 2));
        tm = fmaxf(tm, __shfl_xor(tm, 4));
        tm = fmaxf(tm, __shfl_xor(tm, 8));
        const float mn = fmaxf(mst[mt][r], tm);
        const float al = __expf(mst[mt][r] - mn);  // 0 on first chunk
        mst[mt][r] = mn;
        float rs = 0.f;
#pragma unroll
        for (int tt = 0; tt < 4; tt++) {
          const float p = __expf(s[mt][tt][r] - mn);
          s[mt][tt][r] = p;
          rs += p;
        }
        lsum[mt][r] = lsum[mt][r] * al + rs;
#pragma unroll
        for (int dt = 0; dt < 4; dt++) o[mt][dt][r] *= al;
      }
#pragma unroll
      for (int tt = 0; tt < 4; tt++)
#pragma unroll
        for (int r = 0; r < 4; r++)
          Pbuf[w][mt][quad * 4 + r][tt * 16 + l16] = (bf16_t)s[mt][tt][r];
    }

    bf16x8 vb[4][2];
#pragma unroll
    for (int dt = 0; dt < 4; dt++)
#pragma unroll
      for (int hf = 0; hf < 2; hf++)
        vb[dt][hf] = *(const bf16x8*)&Vt[(size_t)(h * 64 + dt * 16 + l16) * L +
                                         j0 + hf * 32 + quad * 8];
#pragma unroll
    for (int mt = 0; mt < 2; mt++) {
      const bf16x8 pa0 = *(const bf16x8*)&Pbuf[w][mt][l16][quad * 8];
      const bf16x8 pa1 = *(const bf16x8*)&Pbuf[w][mt][l16][32 + quad * 8];
#pragma unroll
      for (int dt = 0; dt < 4; dt++) {
        o[mt][dt] = MFMA_BF16(pa0, vb[dt][0], o[mt][dt], 0, 0, 0);
        o[mt][dt] = MFMA_BF16(pa1, vb[dt][1], o[mt][dt], 0, 0, 0);
      }
    }
  }

#pragma unroll
  for (int mt = 0; mt < 2; mt++)
#pragma unroll
    for (int r = 0; r < 4; r++) {
      float l = lsum[mt][r];
      l += __shfl_xor(l, 1);
      l += __shfl_xor(l, 2);
      l += __shfl_xor(l, 4);
      l += __shfl_xor(l, 8);
      const float inv = 1.0f / l;
      const size_t row = (size_t)(qbase + mt * 16 + quad * 4 + r);
#pragma unroll
      for (int dt = 0; dt < 4; dt++)
        O[row * 1024 + h * 64 + dt * 16 + l16] = (bf16_t)(o[mt][dt][r] * inv);
    }
}

// ---------------------------------------------------------------------------
extern "C" void kernel_launch(void* const* d_in, const int* in_sizes, int n_in,
                              void* d_out, int out_size, void* d_ws,
                              size_t ws_size, hipStream_t stream) {
  const float* q  = (const float*)d_in[0];
  const float* k  = (const float*)d_in[1];
  const float* v  = (const float*)d_in[2];
  const float* wq = (const float*)d_in[3];
  const float* bq = (const float*)d_in[4];
  const float* wk = (const float*)d_in[5];
  const float* bk = (const float*)d_in[6];
  const float* wv = (const float*)d_in[7];
  const float* bv = (const float*)d_in[8];
  const float* wo = (const float*)d_in[9];
  const float* bo = (const float*)d_in[10];
  float* out = (float*)d_out;  // fp32 output per reference dtype

  const int L = 4096, D = 1024;
  const int nLD = L * D;      // 4M
  const int nDD = D * D;      // 1M
  bf16_t* p = (bf16_t*)d_ws;
  bf16_t* qb  = p; p += nLD;
  bf16_t* kb  = p; p += nLD;
  bf16_t* vb  = p; p += nLD;
  bf16_t* wqb = p; p += nDD;
  bf16_t* wkb = p; p += nDD;
  bf16_t* wvb = p; p += nDD;
  bf16_t* wob = p; p += nDD;
  bf16_t* Qp  = p; p += nLD;
  bf16_t* Kp  = p; p += nLD;
  bf16_t* Vp  = p; p += nLD;
  bf16_t* Vtp = p; p += nLD;
  bf16_t* Op  = Vp;  // reuse V after transpose consumed it

  dim3 blk(256);
  // fp32 -> bf16 casts (z = tensor id)
  cast_f32_bf16<<<dim3(nLD / (256 * 8), 1, 7), blk, 0, stream>>>(
      q, qb, nLD, k, kb, nLD, v, vb, nLD, wq, wqb, nDD, wk, wkb, nDD,
      wv, wvb, nDD, wo, wob, nDD);
  // Q/K/V projections
  gemm3_bt<bf16_t><<<dim3(L / 128, D / 64, 3), blk, 0, stream>>>(
      qb, wqb, bq, Qp, kb, wkb, bk, Kp, vb, wvb, bv, Vp, L, D, D);
  // V -> V^T per head
  transpose_v<<<dim3(L / 64, 16), blk, 0, stream>>>((const ushort*)Vp,
                                                    (ushort*)Vtp);
  // attention
  flash_attn<<<dim3(L / 128, 16), blk, 0, stream>>>(Qp, Kp, Vtp, Op, L);
  // output projection -> fp32 d_out
  gemm3_bt<float><<<dim3(L / 128, D / 64, 1), blk, 0, stream>>>(
      Op, wob, bo, out, Op, wob, bo, out, Op, wob, bo, out, L, D, D);
}